// Round 2
// baseline (19902.705 us; speedup 1.0000x reference)
//
#include <hip/hip_runtime.h>
#include <cmath>
#include <cstdint>

#define VOCAB 32000
#define HID   1024
#define BATCH 16
#define SEQ   256

// ---------------------------------------------------------------------------
// WhT[l][k][n] = Wh[l][n][k]  (transpose both layers' recurrent weights)
// ---------------------------------------------------------------------------
__global__ __launch_bounds__(256) void transpose_wh(
    const float* __restrict__ Wh, float* __restrict__ WhT)
{
  __shared__ float tile[32][33];
  const float* src = Wh + (size_t)blockIdx.z * HID * HID;
  float*       dst = WhT + (size_t)blockIdx.z * HID * HID;
  int x0 = blockIdx.x * 32, y0 = blockIdx.y * 32;
  int tx = threadIdx.x & 31, ty0 = threadIdx.x >> 5;
  for (int r = ty0; r < 32; r += 8)
    tile[r][tx] = src[(size_t)(y0 + r) * HID + x0 + tx];
  __syncthreads();
  for (int r = ty0; r < 32; r += 8)
    dst[(size_t)(x0 + r) * HID + y0 + tx] = tile[tx][r];
}

// ---------------------------------------------------------------------------
// pre0[t][b][n] = embed[x[b][t]] . Wi0[n] + bi0[n] + bh0[n]
// M=4096 (m = t*16+b), N=1024, K=1024
// ---------------------------------------------------------------------------
__global__ __launch_bounds__(256) void pre0_gemm(
    const int* __restrict__ x, const float* __restrict__ embed,
    const float* __restrict__ Wi0, const float* __restrict__ bi0,
    const float* __restrict__ bh0, float* __restrict__ pre)
{
  __shared__ float As[32][132];
  __shared__ float Bs[32][132];
  const int tid  = threadIdx.x;
  const int n0   = blockIdx.x * 128;
  const int m0   = blockIdx.y * 128;
  const int lrow = tid >> 3, lkq = tid & 7;
  const int ty   = tid >> 4, tx  = tid & 15;

  const float* arow[4];
#pragma unroll
  for (int q = 0; q < 4; ++q) {
    int m = m0 + lrow + 32 * q;
    int t = m >> 4, b = m & 15;
    arow[q] = embed + (size_t)x[b * SEQ + t] * HID;
  }
  const float* brow = Wi0 + (size_t)(n0 + lrow) * HID;

  float acc[8][8];
#pragma unroll
  for (int i = 0; i < 8; ++i)
#pragma unroll
    for (int j = 0; j < 8; ++j) acc[i][j] = 0.f;

  for (int kt = 0; kt < HID; kt += 32) {
    float4 av[4], bv[4];
#pragma unroll
    for (int q = 0; q < 4; ++q) {
      av[q] = *(const float4*)(arow[q] + kt + lkq * 4);
      bv[q] = *(const float4*)(brow + (size_t)(32 * q) * HID + kt + lkq * 4);
    }
    __syncthreads();
#pragma unroll
    for (int q = 0; q < 4; ++q) {
      int r = lrow + 32 * q;
      As[lkq*4+0][r] = av[q].x; As[lkq*4+1][r] = av[q].y;
      As[lkq*4+2][r] = av[q].z; As[lkq*4+3][r] = av[q].w;
      Bs[lkq*4+0][r] = bv[q].x; Bs[lkq*4+1][r] = bv[q].y;
      Bs[lkq*4+2][r] = bv[q].z; Bs[lkq*4+3][r] = bv[q].w;
    }
    __syncthreads();
#pragma unroll
    for (int kk = 0; kk < 32; ++kk) {
      float4 a0 = *(const float4*)&As[kk][ty * 8];
      float4 a1 = *(const float4*)&As[kk][ty * 8 + 4];
      float4 b0 = *(const float4*)&Bs[kk][tx * 8];
      float4 b1 = *(const float4*)&Bs[kk][tx * 8 + 4];
      float a[8] = {a0.x,a0.y,a0.z,a0.w,a1.x,a1.y,a1.z,a1.w};
      float b[8] = {b0.x,b0.y,b0.z,b0.w,b1.x,b1.y,b1.z,b1.w};
#pragma unroll
      for (int i = 0; i < 8; ++i)
#pragma unroll
        for (int j = 0; j < 8; ++j) acc[i][j] = fmaf(a[i], b[j], acc[i][j]);
    }
  }

#pragma unroll
  for (int i = 0; i < 8; ++i) {
    int m = m0 + ty * 8 + i;
    float* o = pre + (size_t)m * HID + n0 + tx * 8;
#pragma unroll
    for (int j = 0; j < 8; ++j) {
      int n = n0 + tx * 8 + j;
      o[j] = acc[i][j] + bi0[n] + bh0[n];
    }
  }
}

// ---------------------------------------------------------------------------
// pre1[m][n] = A[m] . Wi1[n] + bi1[n] + bh1[n]   (A = h0all, m = t*16+b)
// ---------------------------------------------------------------------------
__global__ __launch_bounds__(256) void pre1_gemm(
    const float* __restrict__ A, const float* __restrict__ Wi1,
    const float* __restrict__ bi1, const float* __restrict__ bh1,
    float* __restrict__ pre)
{
  __shared__ float As[32][132];
  __shared__ float Bs[32][132];
  const int tid  = threadIdx.x;
  const int n0   = blockIdx.x * 128;
  const int m0   = blockIdx.y * 128;
  const int lrow = tid >> 3, lkq = tid & 7;
  const int ty   = tid >> 4, tx  = tid & 15;

  const float* arow[4];
#pragma unroll
  for (int q = 0; q < 4; ++q)
    arow[q] = A + (size_t)(m0 + lrow + 32 * q) * HID;
  const float* brow = Wi1 + (size_t)(n0 + lrow) * HID;

  float acc[8][8];
#pragma unroll
  for (int i = 0; i < 8; ++i)
#pragma unroll
    for (int j = 0; j < 8; ++j) acc[i][j] = 0.f;

  for (int kt = 0; kt < HID; kt += 32) {
    float4 av[4], bv[4];
#pragma unroll
    for (int q = 0; q < 4; ++q) {
      av[q] = *(const float4*)(arow[q] + kt + lkq * 4);
      bv[q] = *(const float4*)(brow + (size_t)(32 * q) * HID + kt + lkq * 4);
    }
    __syncthreads();
#pragma unroll
    for (int q = 0; q < 4; ++q) {
      int r = lrow + 32 * q;
      As[lkq*4+0][r] = av[q].x; As[lkq*4+1][r] = av[q].y;
      As[lkq*4+2][r] = av[q].z; As[lkq*4+3][r] = av[q].w;
      Bs[lkq*4+0][r] = bv[q].x; Bs[lkq*4+1][r] = bv[q].y;
      Bs[lkq*4+2][r] = bv[q].z; Bs[lkq*4+3][r] = bv[q].w;
    }
    __syncthreads();
#pragma unroll
    for (int kk = 0; kk < 32; ++kk) {
      float4 a0 = *(const float4*)&As[kk][ty * 8];
      float4 a1 = *(const float4*)&As[kk][ty * 8 + 4];
      float4 b0 = *(const float4*)&Bs[kk][tx * 8];
      float4 b1 = *(const float4*)&Bs[kk][tx * 8 + 4];
      float a[8] = {a0.x,a0.y,a0.z,a0.w,a1.x,a1.y,a1.z,a1.w};
      float b[8] = {b0.x,b0.y,b0.z,b0.w,b1.x,b1.y,b1.z,b1.w};
#pragma unroll
      for (int i = 0; i < 8; ++i)
#pragma unroll
        for (int j = 0; j < 8; ++j) acc[i][j] = fmaf(a[i], b[j], acc[i][j]);
    }
  }

#pragma unroll
  for (int i = 0; i < 8; ++i) {
    int m = m0 + ty * 8 + i;
    float* o = pre + (size_t)m * HID + n0 + tx * 8;
#pragma unroll
    for (int j = 0; j < 8; ++j) {
      int n = n0 + tx * 8 + j;
      o[j] = acc[i][j] + bi1[n] + bh1[n];
    }
  }
}

// ---------------------------------------------------------------------------
// Per-batch recurrent scan for one layer. 16 blocks (one per batch element),
// 1024 threads. h kept in LDS; weights read as WhT[k][n] (coalesced, L2-hot).
// Thread (kg, ng) accumulates k-quarter kg for outputs n = ng*4..ng*4+3;
// partials combined via LDS each step.
//   out[t][b][n] = tanh(pre[t][b][n] + sum_k h_prev[k] * WhT[k][n])
// ---------------------------------------------------------------------------
__global__ __launch_bounds__(1024) void scan_layer(
    const float* __restrict__ WhT, const float* __restrict__ pre,
    float* __restrict__ outbuf)
{
  __shared__ float h_s[HID];
  __shared__ float part[4][256][4];     // 16 KiB partial sums
  const int tid = threadIdx.x;
  const int b   = blockIdx.x;
  const int kg  = tid >> 8;             // k-quarter 0..3
  const int ng  = tid & 255;            // output group (4 outputs)

  h_s[tid] = 0.f;
  __syncthreads();

  const float* wbase = WhT + (size_t)(kg * 256) * HID + ng * 4;

  for (int t = 0; t < SEQ; ++t) {
    const float* hp = &h_s[kg * 256];
    float ax = 0.f, ay = 0.f, az = 0.f, aw = 0.f;
#pragma unroll 8
    for (int k = 0; k < 256; ++k) {
      float hv = hp[k];
      float4 wv = *(const float4*)(wbase + (size_t)k * HID);
      ax = fmaf(hv, wv.x, ax); ay = fmaf(hv, wv.y, ay);
      az = fmaf(hv, wv.z, az); aw = fmaf(hv, wv.w, aw);
    }
    part[kg][ng][0] = ax; part[kg][ng][1] = ay;
    part[kg][ng][2] = az; part[kg][ng][3] = aw;
    __syncthreads();

    float s = pre[(size_t)(t * BATCH + b) * HID + tid]
            + part[0][tid >> 2][tid & 3] + part[1][tid >> 2][tid & 3]
            + part[2][tid >> 2][tid & 3] + part[3][tid >> 2][tid & 3];
    float v = tanhf(s);
    h_s[tid] = v;                                   // old h fully consumed
    outbuf[(size_t)(t * BATCH + b) * HID + tid] = v;
    __syncthreads();
  }
}

// ---------------------------------------------------------------------------
// logits[b][s][v] = tops[s][b][:] . Wo[v][:] + bo[v]
// M=4096 (m = b*256+s for contiguous C writes), N=32000, K=1024
// ---------------------------------------------------------------------------
__global__ __launch_bounds__(256) void proj_gemm(
    const float* __restrict__ tops, const float* __restrict__ Wo,
    const float* __restrict__ bo, float* __restrict__ out)
{
  __shared__ float As[32][132];
  __shared__ float Bs[32][132];
  const int tid  = threadIdx.x;
  const int n0   = blockIdx.x * 128;       // 250 blocks
  const int m0   = blockIdx.y * 128;       // 32 blocks
  const int lrow = tid >> 3, lkq = tid & 7;
  const int ty   = tid >> 4, tx  = tid & 15;

  const float* arow[4];
#pragma unroll
  for (int q = 0; q < 4; ++q) {
    int m = m0 + lrow + 32 * q;
    int b = m >> 8, s = m & 255;
    arow[q] = tops + (size_t)(s * BATCH + b) * HID;
  }
  const float* brow = Wo + (size_t)(n0 + lrow) * HID;

  float acc[8][8];
#pragma unroll
  for (int i = 0; i < 8; ++i)
#pragma unroll
    for (int j = 0; j < 8; ++j) acc[i][j] = 0.f;

  for (int kt = 0; kt < HID; kt += 32) {
    float4 av[4], bv[4];
#pragma unroll
    for (int q = 0; q < 4; ++q) {
      av[q] = *(const float4*)(arow[q] + kt + lkq * 4);
      bv[q] = *(const float4*)(brow + (size_t)(32 * q) * HID + kt + lkq * 4);
    }
    __syncthreads();
#pragma unroll
    for (int q = 0; q < 4; ++q) {
      int r = lrow + 32 * q;
      As[lkq*4+0][r] = av[q].x; As[lkq*4+1][r] = av[q].y;
      As[lkq*4+2][r] = av[q].z; As[lkq*4+3][r] = av[q].w;
      Bs[lkq*4+0][r] = bv[q].x; Bs[lkq*4+1][r] = bv[q].y;
      Bs[lkq*4+2][r] = bv[q].z; Bs[lkq*4+3][r] = bv[q].w;
    }
    __syncthreads();
#pragma unroll
    for (int kk = 0; kk < 32; ++kk) {
      float4 a0 = *(const float4*)&As[kk][ty * 8];
      float4 a1 = *(const float4*)&As[kk][ty * 8 + 4];
      float4 b0 = *(const float4*)&Bs[kk][tx * 8];
      float4 b1 = *(const float4*)&Bs[kk][tx * 8 + 4];
      float a[8] = {a0.x,a0.y,a0.z,a0.w,a1.x,a1.y,a1.z,a1.w};
      float b[8] = {b0.x,b0.y,b0.z,b0.w,b1.x,b1.y,b1.z,b1.w};
#pragma unroll
      for (int i = 0; i < 8; ++i)
#pragma unroll
        for (int j = 0; j < 8; ++j) acc[i][j] = fmaf(a[i], b[j], acc[i][j]);
    }
  }

#pragma unroll
  for (int i = 0; i < 8; ++i) {
    int m = m0 + ty * 8 + i;
    float* o = out + (size_t)m * VOCAB + n0 + tx * 8;
#pragma unroll
    for (int j = 0; j < 8; ++j) o[j] = acc[i][j] + bo[n0 + tx * 8 + j];
  }
}

// hidden[0][b][n] = h0all[255][b][n]; hidden[1][b][n] = tops[255][b][n]
__global__ void copy_hidden(const float* __restrict__ h0all,
                            const float* __restrict__ tops,
                            float* __restrict__ outh)
{
  int i = blockIdx.x * 256 + threadIdx.x;   // 0..32767
  int l = i >> 14, rem = i & 16383;
  size_t src = (size_t)(SEQ - 1) * (BATCH * HID) + rem;
  outh[i] = (l == 0) ? h0all[src] : tops[src];
}

extern "C" void kernel_launch(void* const* d_in, const int* in_sizes, int n_in,
                              void* d_out, int out_size, void* d_ws, size_t ws_size,
                              hipStream_t stream)
{
  const int*   x     = (const int*)d_in[0];
  const float* embed = (const float*)d_in[1];
  const float* Wi    = (const float*)d_in[2];
  const float* bi    = (const float*)d_in[3];
  const float* Wh    = (const float*)d_in[4];
  const float* bh    = (const float*)d_in[5];
  const float* Wo    = (const float*)d_in[6];
  const float* bo    = (const float*)d_in[7];
  float* out = (float*)d_out;

  char* ws = (char*)d_ws;
  float* pre   = (float*)(ws);                   // 16 MiB (pre0, then pre1)
  float* h0all = (float*)(ws + (16u << 20));     // 16 MiB  [t][b][n]
  float* tops  = (float*)(ws + (32u << 20));     // 16 MiB  [t][b][n]
  float* WhT   = (float*)(ws + (48u << 20));     // 8 MiB   [l][k][n]

  dim3 blk(256);
  transpose_wh<<<dim3(32, 32, 2), blk, 0, stream>>>(Wh, WhT);
  pre0_gemm<<<dim3(8, 32), blk, 0, stream>>>(x, embed, Wi, bi, bh, pre);
  scan_layer<<<dim3(16), dim3(1024), 0, stream>>>(WhT, pre, h0all);
  pre1_gemm<<<dim3(8, 32), blk, 0, stream>>>(
      h0all, Wi + (size_t)HID * HID, bi + HID, bh + HID, pre);
  scan_layer<<<dim3(16), dim3(1024), 0, stream>>>(WhT + (size_t)HID * HID, pre, tops);
  proj_gemm<<<dim3(250, 32), blk, 0, stream>>>(tops, Wo, bo, out);
  copy_hidden<<<dim3(128), blk, 0, stream>>>(h0all, tops,
                                             out + (size_t)BATCH * SEQ * VOCAB);
}

// Round 3
// 7932.186 us; speedup vs baseline: 2.5091x; 2.5091x over previous
//
#include <hip/hip_runtime.h>
#include <hip/hip_cooperative_groups.h>
#include <cmath>
#include <cstdint>

namespace cg = cooperative_groups;

#define VOCAB 32000
#define HID   1024
#define BATCH 16
#define SEQ   256

typedef __attribute__((ext_vector_type(8))) short short8;
typedef __attribute__((ext_vector_type(4))) float f32x4;

__device__ __forceinline__ ushort f2bf(float f) {  // RNE fp32 -> bf16 bits
  uint u = __builtin_bit_cast(uint, f);
  return (ushort)((u + 0x7FFFu + ((u >> 16) & 1u)) >> 16);
}
__device__ __forceinline__ float bf2f(ushort h) {
  return __builtin_bit_cast(float, (uint)h << 16);
}

// ---------------------------------------------------------------------------
// pre0[t][b][n] = embed[x[b][t]] . Wi0[n] + bi0[n] + bh0[n]
// M=4096 (m=t*16+b), N=1024, K=1024. fp32 tiled GEMM (unchanged).
// ---------------------------------------------------------------------------
__global__ __launch_bounds__(256) void pre0_gemm(
    const int* __restrict__ x, const float* __restrict__ embed,
    const float* __restrict__ Wi0, const float* __restrict__ bi0,
    const float* __restrict__ bh0, float* __restrict__ pre)
{
  __shared__ float As[32][132];
  __shared__ float Bs[32][132];
  const int tid  = threadIdx.x;
  const int n0   = blockIdx.x * 128;
  const int m0   = blockIdx.y * 128;
  const int lrow = tid >> 3, lkq = tid & 7;
  const int ty   = tid >> 4, tx  = tid & 15;

  const float* arow[4];
#pragma unroll
  for (int q = 0; q < 4; ++q) {
    int m = m0 + lrow + 32 * q;
    int t = m >> 4, b = m & 15;
    arow[q] = embed + (size_t)x[b * SEQ + t] * HID;
  }
  const float* brow = Wi0 + (size_t)(n0 + lrow) * HID;

  float acc[8][8];
#pragma unroll
  for (int i = 0; i < 8; ++i)
#pragma unroll
    for (int j = 0; j < 8; ++j) acc[i][j] = 0.f;

  for (int kt = 0; kt < HID; kt += 32) {
    float4 av[4], bv[4];
#pragma unroll
    for (int q = 0; q < 4; ++q) {
      av[q] = *(const float4*)(arow[q] + kt + lkq * 4);
      bv[q] = *(const float4*)(brow + (size_t)(32 * q) * HID + kt + lkq * 4);
    }
    __syncthreads();
#pragma unroll
    for (int q = 0; q < 4; ++q) {
      int r = lrow + 32 * q;
      As[lkq*4+0][r] = av[q].x; As[lkq*4+1][r] = av[q].y;
      As[lkq*4+2][r] = av[q].z; As[lkq*4+3][r] = av[q].w;
      Bs[lkq*4+0][r] = bv[q].x; Bs[lkq*4+1][r] = bv[q].y;
      Bs[lkq*4+2][r] = bv[q].z; Bs[lkq*4+3][r] = bv[q].w;
    }
    __syncthreads();
#pragma unroll
    for (int kk = 0; kk < 32; ++kk) {
      float4 a0 = *(const float4*)&As[kk][ty * 8];
      float4 a1 = *(const float4*)&As[kk][ty * 8 + 4];
      float4 b0 = *(const float4*)&Bs[kk][tx * 8];
      float4 b1 = *(const float4*)&Bs[kk][tx * 8 + 4];
      float a[8] = {a0.x,a0.y,a0.z,a0.w,a1.x,a1.y,a1.z,a1.w};
      float b[8] = {b0.x,b0.y,b0.z,b0.w,b1.x,b1.y,b1.z,b1.w};
#pragma unroll
      for (int i = 0; i < 8; ++i)
#pragma unroll
        for (int j = 0; j < 8; ++j) acc[i][j] = fmaf(a[i], b[j], acc[i][j]);
    }
  }

#pragma unroll
  for (int i = 0; i < 8; ++i) {
    int m = m0 + ty * 8 + i;
    float* o = pre + (size_t)m * HID + n0 + tx * 8;
#pragma unroll
    for (int j = 0; j < 8; ++j) {
      int n = n0 + tx * 8 + j;
      o[j] = acc[i][j] + bi0[n] + bh0[n];
    }
  }
}

// ---------------------------------------------------------------------------
// Fused skewed cooperative scan. 192 blocks x 512 threads, 1 grid.sync/tick.
//  Blocks 0..63  (L0): own 16 rows of Wh0 (LDS, transposed [k][16]).
//     tick u<256: h0[u] = tanh(pre0[u] + Wh0 . h0[u-1])
//  Blocks 64..191 (L1): own 8 rows of [Wi1|Wh1] (LDS, transposed [2048][8]).
//     tick u>=1, t=u-1: h1[t] = tanh(Wi1.h0[t] + Wh1.h1[t-1] + bi1 + bh1)
// h0g/h1g: [2][16][1024] parity double-buffers in ws (pre-zeroed).
// ---------------------------------------------------------------------------
__global__ __launch_bounds__(512) void rnn_scan(
    const float* __restrict__ Wi, const float* __restrict__ Wh,
    const float* __restrict__ bi, const float* __restrict__ bh,
    const float* __restrict__ pre0, float* __restrict__ h0g,
    float* __restrict__ h1g, float* __restrict__ tops)
{
  cg::grid_group grid = cg::this_grid();
  __shared__ float wT[16 * 1024];   // L0: [k][16]; L1: [k2][8], k2<2048
  __shared__ float hT[1024 * 16];   // [k][16] staged h
  __shared__ float part[2048];
  __shared__ float bias[8];

  const int tid = threadIdx.x;
  const int blk = blockIdx.x;
  const bool isL0 = (blk < 64);

  // ---- one-time: load transposed weights into LDS ----
  if (isL0) {
    const int j = blk;                       // rows 16j..16j+15 of Wh0
#pragma unroll
    for (int p = 0; p < 8; ++p) {
      int idx = tid + 512 * p;               // float4 index 0..4095
      int r = idx >> 8, kq = idx & 255;
      float4 v = *(const float4*)(Wh + ((size_t)(16 * j + r)) * HID + 4 * kq);
      wT[(4*kq+0)*16 + r] = v.x; wT[(4*kq+1)*16 + r] = v.y;
      wT[(4*kq+2)*16 + r] = v.z; wT[(4*kq+3)*16 + r] = v.w;
    }
  } else {
    const int j = blk - 64;                  // rows 8j..8j+7
#pragma unroll
    for (int p = 0; p < 8; ++p) {
      int idx = tid + 512 * p;               // 0..4095; first half Wi1, rest Wh1
      int half = idx >> 11;
      int id2 = idx & 2047;
      int r = id2 >> 8, kq = id2 & 255;
      const float* W = (half ? Wh : Wi) + (size_t)HID * HID;
      float4 v = *(const float4*)(W + ((size_t)(8 * j + r)) * HID + 4 * kq);
      int kb = half * 1024 + 4 * kq;
      wT[(kb+0)*8 + r] = v.x; wT[(kb+1)*8 + r] = v.y;
      wT[(kb+2)*8 + r] = v.z; wT[(kb+3)*8 + r] = v.w;
    }
    if (tid < 8) bias[tid] = bi[HID + 8 * j + tid] + bh[HID + 8 * j + tid];
  }
  __syncthreads();

  // stage 16x1024 h (global [b][k]) into hT[k][16]
  auto stage_h = [&](const float* src) {
#pragma unroll
    for (int p = 0; p < 8; ++p) {
      int i = tid + 512 * p;                 // float4 index 0..4095
      int b = i & 15, kq = i >> 4;           // kq 0..255
      float4 v = *(const float4*)(src + (size_t)b * HID + 4 * kq);
      hT[(4*kq+0)*16 + b] = v.x; hT[(4*kq+1)*16 + b] = v.y;
      hT[(4*kq+2)*16 + b] = v.z; hT[(4*kq+3)*16 + b] = v.w;
    }
  };

  for (int u = 0; u <= SEQ; ++u) {
    if (isL0) {
      if (u < SEQ) {
        stage_h(h0g + ((u - 1) & 1) * (BATCH * HID));
        __syncthreads();
        const int bq = tid & 3, rq = (tid >> 2) & 3, ks = tid >> 4;  // ks 0..31
        float acc[4][4] = {{0.f}};
#pragma unroll 4
        for (int i = 0; i < 32; ++i) {
          int k = ks + 32 * i;
          float4 hv = *(const float4*)&hT[k * 16 + 4 * bq];
          float4 wv = *(const float4*)&wT[k * 16 + 4 * rq];
          float hb[4] = {hv.x, hv.y, hv.z, hv.w};
          float wr[4] = {wv.x, wv.y, wv.z, wv.w};
#pragma unroll
          for (int bi_ = 0; bi_ < 4; ++bi_)
#pragma unroll
            for (int rj = 0; rj < 4; ++rj)
              acc[bi_][rj] = fmaf(hb[bi_], wr[rj], acc[bi_][rj]);
        }
#pragma unroll
        for (int bi_ = 0; bi_ < 4; ++bi_)
#pragma unroll
          for (int rj = 0; rj < 4; ++rj) {
            float v = acc[bi_][rj];
            v += __shfl_xor(v, 16); v += __shfl_xor(v, 32);
            acc[bi_][rj] = v;
          }
        const int w = tid >> 6;
        if ((tid & 63) < 16) {
#pragma unroll
          for (int bi_ = 0; bi_ < 4; ++bi_)
#pragma unroll
            for (int rj = 0; rj < 4; ++rj)
              part[w * 256 + (4*bq + bi_) * 16 + 4*rq + rj] = acc[bi_][rj];
        }
        __syncthreads();
        if (tid < 256) {
          int b = tid >> 4, r = tid & 15;
          float s = 0.f;
#pragma unroll
          for (int w2 = 0; w2 < 8; ++w2) s += part[w2 * 256 + b * 16 + r];
          int R = 16 * blk + r;
          s += pre0[((size_t)u * BATCH + b) * HID + R];
          float v = tanhf(s);
          h0g[(u & 1) * (BATCH * HID) + (size_t)b * HID + R] = v;
        }
        __syncthreads();   // hT reusable next tick
      }
    } else {
      if (u >= 1) {
        const int t = u - 1;
        const int bq = tid & 3, rq = (tid >> 2) & 1, ks = tid >> 3;  // ks 0..63
        float acc[4][4] = {{0.f}};
        // phase A: Wi1 . h0[t]
        stage_h(h0g + (t & 1) * (BATCH * HID));
        __syncthreads();
#pragma unroll 4
        for (int i = 0; i < 16; ++i) {
          int k = ks + 64 * i;
          float4 hv = *(const float4*)&hT[k * 16 + 4 * bq];
          float4 wv = *(const float4*)&wT[k * 8 + 4 * rq];
          float hb[4] = {hv.x, hv.y, hv.z, hv.w};
          float wr[4] = {wv.x, wv.y, wv.z, wv.w};
#pragma unroll
          for (int bi_ = 0; bi_ < 4; ++bi_)
#pragma unroll
            for (int rj = 0; rj < 4; ++rj)
              acc[bi_][rj] = fmaf(hb[bi_], wr[rj], acc[bi_][rj]);
        }
        __syncthreads();   // done reading hT
        // phase B: Wh1 . h1[t-1]
        stage_h(h1g + ((t - 1) & 1) * (BATCH * HID));
        __syncthreads();
#pragma unroll 4
        for (int i = 0; i < 16; ++i) {
          int k = ks + 64 * i;
          float4 hv = *(const float4*)&hT[k * 16 + 4 * bq];
          float4 wv = *(const float4*)&wT[(1024 + k) * 8 + 4 * rq];
          float hb[4] = {hv.x, hv.y, hv.z, hv.w};
          float wr[4] = {wv.x, wv.y, wv.z, wv.w};
#pragma unroll
          for (int bi_ = 0; bi_ < 4; ++bi_)
#pragma unroll
            for (int rj = 0; rj < 4; ++rj)
              acc[bi_][rj] = fmaf(hb[bi_], wr[rj], acc[bi_][rj]);
        }
#pragma unroll
        for (int bi_ = 0; bi_ < 4; ++bi_)
#pragma unroll
          for (int rj = 0; rj < 4; ++rj) {
            float v = acc[bi_][rj];
            v += __shfl_xor(v, 8); v += __shfl_xor(v, 16); v += __shfl_xor(v, 32);
            acc[bi_][rj] = v;
          }
        const int w = tid >> 6;
        if ((tid & 63) < 8) {
#pragma unroll
          for (int bi_ = 0; bi_ < 4; ++bi_)
#pragma unroll
            for (int rj = 0; rj < 4; ++rj)
              part[w * 128 + (4*bq + bi_) * 8 + 4*rq + rj] = acc[bi_][rj];
        }
        __syncthreads();
        if (tid < 128) {
          int b = tid >> 3, r = tid & 7;
          float s = bias[r];
#pragma unroll
          for (int w2 = 0; w2 < 8; ++w2) s += part[w2 * 128 + b * 8 + r];
          int R = 8 * (blk - 64) + r;
          float v = tanhf(s);
          tops[((size_t)t * BATCH + b) * HID + R] = v;
          h1g[(t & 1) * (BATCH * HID) + (size_t)b * HID + R] = v;
        }
        __syncthreads();
      }
    }
    grid.sync();
  }
}

// ---------------------------------------------------------------------------
// logits = tops . Wo^T + bo via split-bf16 MFMA (A = hi+lo, B = bf16).
// C[m][n], m=b*256+s, M=4096, N=32000, K=1024. BM=BN=256, BK=64.
// 512 thr = 8 waves as 4m x 2n, wave tile 64x128 (4x8 16x16 frags).
// ---------------------------------------------------------------------------
__global__ __launch_bounds__(512, 1) void proj_mfma(
    const float* __restrict__ tops, const float* __restrict__ Wo,
    const float* __restrict__ bo, float* __restrict__ out)
{
  __shared__ ushort Ahi[256 * 64];
  __shared__ ushort Alo[256 * 64];
  __shared__ ushort Bs [256 * 64];
  const int tid  = threadIdx.x;
  const int m0   = blockIdx.x * 256;    // 16 M-blocks (fastest: share B panel)
  const int n0   = blockIdx.y * 256;    // 125 N-blocks
  const int lane = tid & 63, wv = tid >> 6;
  const int wm   = wv & 3, wn = wv >> 2;
  const int bconst = blockIdx.x;        // batch index for all rows of this block

  f32x4 acc[4][8];
#pragma unroll
  for (int i = 0; i < 4; ++i)
#pragma unroll
    for (int j = 0; j < 8; ++j) acc[i][j] = (f32x4)0.f;

  const int sr = tid >> 4;              // staging row base 0..31
  const int sk = (tid & 15) * 4;        // staging k offset 0..60

  for (int kt = 0; kt < HID; kt += 64) {
    __syncthreads();
#pragma unroll
    for (int p = 0; p < 8; ++p) {       // stage A (tops rows, split hi/lo)
      int r = sr + 32 * p;              // 0..255 ; s=r, b=bconst
      float4 v = *(const float4*)(tops + ((size_t)r * BATCH + bconst) * HID + kt + sk);
      float f[4] = {v.x, v.y, v.z, v.w};
      ushort hi[4], lo[4];
#pragma unroll
      for (int c = 0; c < 4; ++c) {
        hi[c] = f2bf(f[c]);
        lo[c] = f2bf(f[c] - bf2f(hi[c]));
      }
      uint off = (uint)(r * 128 + sk * 2) ^ (uint)((r & 7) << 4);
      *(ushort4*)((char*)Ahi + off) = make_ushort4(hi[0], hi[1], hi[2], hi[3]);
      *(ushort4*)((char*)Alo + off) = make_ushort4(lo[0], lo[1], lo[2], lo[3]);
    }
#pragma unroll
    for (int p = 0; p < 8; ++p) {       // stage B (Wo rows -> bf16)
      int r = sr + 32 * p;
      float4 v = *(const float4*)(Wo + (size_t)(n0 + r) * HID + kt + sk);
      uint off = (uint)(r * 128 + sk * 2) ^ (uint)((r & 7) << 4);
      *(ushort4*)((char*)Bs + off) =
          make_ushort4(f2bf(v.x), f2bf(v.y), f2bf(v.z), f2bf(v.w));
    }
    __syncthreads();

    const int fr = lane & 15, kg = lane >> 4;
#pragma unroll
    for (int kk = 0; kk < 2; ++kk) {
      short8 bf[8], ah[4], al[4];
#pragma unroll
      for (int nf = 0; nf < 8; ++nf) {
        int row = wn * 128 + nf * 16 + fr;
        uint off = (uint)(row * 128 + kk * 64 + kg * 16) ^ (uint)((row & 7) << 4);
        bf[nf] = *(const short8*)((const char*)Bs + off);
      }
#pragma unroll
      for (int mf = 0; mf < 4; ++mf) {
        int row = wm * 64 + mf * 16 + fr;
        uint off = (uint)(row * 128 + kk * 64 + kg * 16) ^ (uint)((row & 7) << 4);
        ah[mf] = *(const short8*)((const char*)Ahi + off);
        al[mf] = *(const short8*)((const char*)Alo + off);
      }
#pragma unroll
      for (int mf = 0; mf < 4; ++mf)
#pragma unroll
        for (int nf = 0; nf < 8; ++nf) {
          acc[mf][nf] = __builtin_amdgcn_mfma_f32_16x16x32_bf16(
              ah[mf], bf[nf], acc[mf][nf], 0, 0, 0);
          acc[mf][nf] = __builtin_amdgcn_mfma_f32_16x16x32_bf16(
              al[mf], bf[nf], acc[mf][nf], 0, 0, 0);
        }
    }
  }

  const int fr = lane & 15, rg = lane >> 4;
#pragma unroll
  for (int mf = 0; mf < 4; ++mf)
#pragma unroll
    for (int nf = 0; nf < 8; ++nf) {
      int n = n0 + wn * 128 + nf * 16 + fr;
      float bb = bo[n];
#pragma unroll
      for (int j = 0; j < 4; ++j) {
        int m = m0 + wm * 64 + mf * 16 + rg * 4 + j;
        out[(size_t)m * VOCAB + n] = acc[mf][nf][j] + bb;
      }
    }
}

// hidden[0][b][n] = h0 step 255 (parity 1); hidden[1][b][n] = tops[255]
__global__ void copy_hidden(const float* __restrict__ h0g,
                            const float* __restrict__ tops,
                            float* __restrict__ outh)
{
  int i = blockIdx.x * 256 + threadIdx.x;   // 0..32767
  int l = i >> 14, rem = i & 16383;
  outh[i] = (l == 0) ? h0g[BATCH * HID + rem]
                     : tops[(size_t)(SEQ - 1) * (BATCH * HID) + rem];
}

extern "C" void kernel_launch(void* const* d_in, const int* in_sizes, int n_in,
                              void* d_out, int out_size, void* d_ws, size_t ws_size,
                              hipStream_t stream)
{
  const int*   x     = (const int*)d_in[0];
  const float* embed = (const float*)d_in[1];
  const float* Wi    = (const float*)d_in[2];
  const float* bi    = (const float*)d_in[3];
  const float* Wh    = (const float*)d_in[4];
  const float* bh    = (const float*)d_in[5];
  const float* Wo    = (const float*)d_in[6];
  const float* bo    = (const float*)d_in[7];
  float* out = (float*)d_out;

  char* ws = (char*)d_ws;
  float* pre0 = (float*)(ws);                          // 16 MiB [t][b][n]
  float* tops = (float*)(ws + (16u << 20));            // 16 MiB [t][b][n]
  float* h0g  = (float*)(ws + (32u << 20));            // 2 x 64 KiB
  float* h1g  = (float*)(ws + (32u << 20) + 131072);   // 2 x 64 KiB

  hipMemsetAsync(h0g, 0, 262144, stream);              // zero both h parities

  pre0_gemm<<<dim3(8, 32), dim3(256), 0, stream>>>(x, embed, Wi, bi, bh, pre0);

  void* args[] = { (void*)&Wi, (void*)&Wh, (void*)&bi, (void*)&bh,
                   (void*)&pre0, (void*)&h0g, (void*)&h1g, (void*)&tops };
  hipLaunchCooperativeKernel((void*)rnn_scan, dim3(192), dim3(512), args, 0, stream);

  proj_mfma<<<dim3(16, 125), dim3(512), 0, stream>>>(tops, Wo, bo, out);

  copy_hidden<<<dim3(128), dim3(256), 0, stream>>>(
      h0g, tops, out + (size_t)BATCH * SEQ * VOCAB);
}

// Round 4
// 4914.350 us; speedup vs baseline: 4.0499x; 1.6141x over previous
//
#include <hip/hip_runtime.h>
#include <cmath>
#include <cstdint>

#define VOCAB 32000
#define HID   1024
#define BATCH 16
#define SEQ   256
#define NBLK  192

typedef __attribute__((ext_vector_type(8))) short short8;
typedef __attribute__((ext_vector_type(4))) float f32x4;

__device__ __forceinline__ ushort f2bf(float f) {  // RNE fp32 -> bf16 bits
  uint u = __builtin_bit_cast(uint, f);
  return (ushort)((u + 0x7FFFu + ((u >> 16) & 1u)) >> 16);
}
__device__ __forceinline__ float bf2f(ushort h) {
  return __builtin_bit_cast(float, (uint)h << 16);
}

// ---------------------------------------------------------------------------
// pre0[t][b][n] = embed[x[b][t]] . Wi0[n] + bi0[n] + bh0[n]
// M=4096 (m=t*16+b), N=1024, K=1024. fp32 tiled GEMM (unchanged).
// ---------------------------------------------------------------------------
__global__ __launch_bounds__(256) void pre0_gemm(
    const int* __restrict__ x, const float* __restrict__ embed,
    const float* __restrict__ Wi0, const float* __restrict__ bi0,
    const float* __restrict__ bh0, float* __restrict__ pre)
{
  __shared__ float As[32][132];
  __shared__ float Bs[32][132];
  const int tid  = threadIdx.x;
  const int n0   = blockIdx.x * 128;
  const int m0   = blockIdx.y * 128;
  const int lrow = tid >> 3, lkq = tid & 7;
  const int ty   = tid >> 4, tx  = tid & 15;

  const float* arow[4];
#pragma unroll
  for (int q = 0; q < 4; ++q) {
    int m = m0 + lrow + 32 * q;
    int t = m >> 4, b = m & 15;
    arow[q] = embed + (size_t)x[b * SEQ + t] * HID;
  }
  const float* brow = Wi0 + (size_t)(n0 + lrow) * HID;

  float acc[8][8];
#pragma unroll
  for (int i = 0; i < 8; ++i)
#pragma unroll
    for (int j = 0; j < 8; ++j) acc[i][j] = 0.f;

  for (int kt = 0; kt < HID; kt += 32) {
    float4 av[4], bv[4];
#pragma unroll
    for (int q = 0; q < 4; ++q) {
      av[q] = *(const float4*)(arow[q] + kt + lkq * 4);
      bv[q] = *(const float4*)(brow + (size_t)(32 * q) * HID + kt + lkq * 4);
    }
    __syncthreads();
#pragma unroll
    for (int q = 0; q < 4; ++q) {
      int r = lrow + 32 * q;
      As[lkq*4+0][r] = av[q].x; As[lkq*4+1][r] = av[q].y;
      As[lkq*4+2][r] = av[q].z; As[lkq*4+3][r] = av[q].w;
      Bs[lkq*4+0][r] = bv[q].x; Bs[lkq*4+1][r] = bv[q].y;
      Bs[lkq*4+2][r] = bv[q].z; Bs[lkq*4+3][r] = bv[q].w;
    }
    __syncthreads();
#pragma unroll
    for (int kk = 0; kk < 32; ++kk) {
      float4 a0 = *(const float4*)&As[kk][ty * 8];
      float4 a1 = *(const float4*)&As[kk][ty * 8 + 4];
      float4 b0 = *(const float4*)&Bs[kk][tx * 8];
      float4 b1 = *(const float4*)&Bs[kk][tx * 8 + 4];
      float a[8] = {a0.x,a0.y,a0.z,a0.w,a1.x,a1.y,a1.z,a1.w};
      float b[8] = {b0.x,b0.y,b0.z,b0.w,b1.x,b1.y,b1.z,b1.w};
#pragma unroll
      for (int i = 0; i < 8; ++i)
#pragma unroll
        for (int j = 0; j < 8; ++j) acc[i][j] = fmaf(a[i], b[j], acc[i][j]);
    }
  }

#pragma unroll
  for (int i = 0; i < 8; ++i) {
    int m = m0 + ty * 8 + i;
    float* o = pre + (size_t)m * HID + n0 + tx * 8;
#pragma unroll
    for (int j = 0; j < 8; ++j) {
      int n = n0 + tx * 8 + j;
      o[j] = acc[i][j] + bi0[n] + bh0[n];
    }
  }
}

// ---------------------------------------------------------------------------
// Fused skewed cooperative scan, custom agent-scope barrier (no cg::grid.sync).
//  Blocks 0..63  (L0): 16 rows of Wh0 in LDS;  tick u<256 computes h0[u].
//  Blocks 64..191 (L1): 8 rows of [Wi1|Wh1];   tick u>=1 computes h1[u-1].
// One barrier per tick. bar is a monotone counter zeroed before launch.
// ---------------------------------------------------------------------------
__global__ __launch_bounds__(512) void rnn_scan(
    const float* __restrict__ Wi, const float* __restrict__ Wh,
    const float* __restrict__ bi, const float* __restrict__ bh,
    const float* __restrict__ pre0, float* __restrict__ h0g,
    float* __restrict__ h1g, float* __restrict__ tops,
    int* __restrict__ bar)
{
  __shared__ float wT[16 * 1024];   // L0: [k][16]; L1: [k2][8], k2<2048
  __shared__ float hT[1024 * 16];   // [k][16] staged h
  __shared__ float part[2048];
  __shared__ float bias[8];

  const int tid = threadIdx.x;
  const int blk = blockIdx.x;
  const bool isL0 = (blk < 64);

  // ---- one-time: load transposed weights into LDS ----
  if (isL0) {
    const int j = blk;                       // rows 16j..16j+15 of Wh0
#pragma unroll
    for (int p = 0; p < 8; ++p) {
      int idx = tid + 512 * p;               // float4 index 0..4095
      int r = idx >> 8, kq = idx & 255;
      float4 v = *(const float4*)(Wh + ((size_t)(16 * j + r)) * HID + 4 * kq);
      wT[(4*kq+0)*16 + r] = v.x; wT[(4*kq+1)*16 + r] = v.y;
      wT[(4*kq+2)*16 + r] = v.z; wT[(4*kq+3)*16 + r] = v.w;
    }
  } else {
    const int j = blk - 64;                  // rows 8j..8j+7
#pragma unroll
    for (int p = 0; p < 8; ++p) {
      int idx = tid + 512 * p;               // 0..4095; first half Wi1, rest Wh1
      int half = idx >> 11;
      int id2 = idx & 2047;
      int r = id2 >> 8, kq = id2 & 255;
      const float* W = (half ? Wh : Wi) + (size_t)HID * HID;
      float4 v = *(const float4*)(W + ((size_t)(8 * j + r)) * HID + 4 * kq);
      int kb = half * 1024 + 4 * kq;
      wT[(kb+0)*8 + r] = v.x; wT[(kb+1)*8 + r] = v.y;
      wT[(kb+2)*8 + r] = v.z; wT[(kb+3)*8 + r] = v.w;
    }
    if (tid < 8) bias[tid] = bi[HID + 8 * j + tid] + bh[HID + 8 * j + tid];
  }
  __syncthreads();

  // stage 16x1024 h (global [b][k]) into hT[k][16]
  auto stage_h = [&](const float* src) {
#pragma unroll
    for (int p = 0; p < 8; ++p) {
      int i = tid + 512 * p;                 // float4 index 0..4095
      int b = i & 15, kq = i >> 4;           // kq 0..255
      float4 v = *(const float4*)(src + (size_t)b * HID + 4 * kq);
      hT[(4*kq+0)*16 + b] = v.x; hT[(4*kq+1)*16 + b] = v.y;
      hT[(4*kq+2)*16 + b] = v.z; hT[(4*kq+3)*16 + b] = v.w;
    }
  };

  for (int u = 0; u <= SEQ; ++u) {
    if (isL0) {
      if (u < SEQ) {
        stage_h(h0g + ((u - 1) & 1) * (BATCH * HID));
        __syncthreads();
        const int bq = tid & 3, rq = (tid >> 2) & 3, ks = tid >> 4;  // ks 0..31
        float acc[4][4] = {{0.f}};
#pragma unroll 4
        for (int i = 0; i < 32; ++i) {
          int k = ks + 32 * i;
          float4 hv = *(const float4*)&hT[k * 16 + 4 * bq];
          float4 wv = *(const float4*)&wT[k * 16 + 4 * rq];
          float hb[4] = {hv.x, hv.y, hv.z, hv.w};
          float wr[4] = {wv.x, wv.y, wv.z, wv.w};
#pragma unroll
          for (int bi_ = 0; bi_ < 4; ++bi_)
#pragma unroll
            for (int rj = 0; rj < 4; ++rj)
              acc[bi_][rj] = fmaf(hb[bi_], wr[rj], acc[bi_][rj]);
        }
#pragma unroll
        for (int bi_ = 0; bi_ < 4; ++bi_)
#pragma unroll
          for (int rj = 0; rj < 4; ++rj) {
            float v = acc[bi_][rj];
            v += __shfl_xor(v, 16); v += __shfl_xor(v, 32);
            acc[bi_][rj] = v;
          }
        const int w = tid >> 6;
        if ((tid & 63) < 16) {
#pragma unroll
          for (int bi_ = 0; bi_ < 4; ++bi_)
#pragma unroll
            for (int rj = 0; rj < 4; ++rj)
              part[w * 256 + (4*bq + bi_) * 16 + 4*rq + rj] = acc[bi_][rj];
        }
        __syncthreads();
        if (tid < 256) {
          int b = tid >> 4, r = tid & 15;
          float s = 0.f;
#pragma unroll
          for (int w2 = 0; w2 < 8; ++w2) s += part[w2 * 256 + b * 16 + r];
          int R = 16 * blk + r;
          s += pre0[((size_t)u * BATCH + b) * HID + R];
          float v = tanhf(s);
          h0g[(u & 1) * (BATCH * HID) + (size_t)b * HID + R] = v;
        }
      }
    } else {
      if (u >= 1) {
        const int t = u - 1;
        const int bq = tid & 3, rq = (tid >> 2) & 1, ks = tid >> 3;  // ks 0..63
        float acc[4][4] = {{0.f}};
        // phase A: Wi1 . h0[t]
        stage_h(h0g + (t & 1) * (BATCH * HID));
        __syncthreads();
#pragma unroll 4
        for (int i = 0; i < 16; ++i) {
          int k = ks + 64 * i;
          float4 hv = *(const float4*)&hT[k * 16 + 4 * bq];
          float4 wv = *(const float4*)&wT[k * 8 + 4 * rq];
          float hb[4] = {hv.x, hv.y, hv.z, hv.w};
          float wr[4] = {wv.x, wv.y, wv.z, wv.w};
#pragma unroll
          for (int bi_ = 0; bi_ < 4; ++bi_)
#pragma unroll
            for (int rj = 0; rj < 4; ++rj)
              acc[bi_][rj] = fmaf(hb[bi_], wr[rj], acc[bi_][rj]);
        }
        __syncthreads();   // done reading hT
        // phase B: Wh1 . h1[t-1]
        stage_h(h1g + ((t - 1) & 1) * (BATCH * HID));
        __syncthreads();
#pragma unroll 4
        for (int i = 0; i < 16; ++i) {
          int k = ks + 64 * i;
          float4 hv = *(const float4*)&hT[k * 16 + 4 * bq];
          float4 wv = *(const float4*)&wT[(1024 + k) * 8 + 4 * rq];
          float hb[4] = {hv.x, hv.y, hv.z, hv.w};
          float wr[4] = {wv.x, wv.y, wv.z, wv.w};
#pragma unroll
          for (int bi_ = 0; bi_ < 4; ++bi_)
#pragma unroll
            for (int rj = 0; rj < 4; ++rj)
              acc[bi_][rj] = fmaf(hb[bi_], wr[rj], acc[bi_][rj]);
        }
#pragma unroll
        for (int bi_ = 0; bi_ < 4; ++bi_)
#pragma unroll
          for (int rj = 0; rj < 4; ++rj) {
            float v = acc[bi_][rj];
            v += __shfl_xor(v, 8); v += __shfl_xor(v, 16); v += __shfl_xor(v, 32);
            acc[bi_][rj] = v;
          }
        const int w = tid >> 6;
        if ((tid & 63) < 8) {
#pragma unroll
          for (int bi_ = 0; bi_ < 4; ++bi_)
#pragma unroll
            for (int rj = 0; rj < 4; ++rj)
              part[w * 128 + (4*bq + bi_) * 8 + 4*rq + rj] = acc[bi_][rj];
        }
        __syncthreads();
        if (tid < 128) {
          int b = tid >> 3, r = tid & 7;
          float s = bias[r];
#pragma unroll
          for (int w2 = 0; w2 < 8; ++w2) s += part[w2 * 128 + b * 8 + r];
          int R = 8 * (blk - 64) + r;
          float v = tanhf(s);
          tops[((size_t)t * BATCH + b) * HID + R] = v;
          h1g[(t & 1) * (BATCH * HID) + (size_t)b * HID + R] = v;
        }
      }
    }

    // ---- custom grid barrier (release-add, relaxed-spin, acquire-load) ----
    __syncthreads();
    if (tid == 0) {
      __hip_atomic_fetch_add(bar, 1, __ATOMIC_RELEASE, __HIP_MEMORY_SCOPE_AGENT);
      const int target = NBLK * (u + 1);
      while (__hip_atomic_load(bar, __ATOMIC_RELAXED, __HIP_MEMORY_SCOPE_AGENT) < target) {}
      (void)__hip_atomic_load(bar, __ATOMIC_ACQUIRE, __HIP_MEMORY_SCOPE_AGENT);
    }
    __syncthreads();
  }
}

// ---------------------------------------------------------------------------
// logits = tops . Wo^T + bo via split-bf16 MFMA (A = hi+lo, B = bf16).
// C[m][n], m=b*256+s, M=4096, N=32000, K=1024. BM=BN=256, BK=64.
// 512 thr = 8 waves as 4m x 2n, wave tile 64x128 (4x8 16x16 frags).
// ---------------------------------------------------------------------------
__global__ __launch_bounds__(512, 1) void proj_mfma(
    const float* __restrict__ tops, const float* __restrict__ Wo,
    const float* __restrict__ bo, float* __restrict__ out)
{
  __shared__ ushort Ahi[256 * 64];
  __shared__ ushort Alo[256 * 64];
  __shared__ ushort Bs [256 * 64];
  const int tid  = threadIdx.x;
  const int m0   = blockIdx.x * 256;    // 16 M-blocks (fastest: share B panel)
  const int n0   = blockIdx.y * 256;    // 125 N-blocks
  const int lane = tid & 63, wv = tid >> 6;
  const int wm   = wv & 3, wn = wv >> 2;
  const int bconst = blockIdx.x;        // batch index for all rows of this block

  f32x4 acc[4][8];
#pragma unroll
  for (int i = 0; i < 4; ++i)
#pragma unroll
    for (int j = 0; j < 8; ++j) acc[i][j] = (f32x4)0.f;

  const int sr = tid >> 4;              // staging row base 0..31
  const int sk = (tid & 15) * 4;        // staging k offset 0..60

  for (int kt = 0; kt < HID; kt += 64) {
    __syncthreads();
#pragma unroll
    for (int p = 0; p < 8; ++p) {       // stage A (tops rows, split hi/lo)
      int r = sr + 32 * p;              // 0..255 ; s=r, b=bconst
      float4 v = *(const float4*)(tops + ((size_t)r * BATCH + bconst) * HID + kt + sk);
      float f[4] = {v.x, v.y, v.z, v.w};
      ushort hi[4], lo[4];
#pragma unroll
      for (int c = 0; c < 4; ++c) {
        hi[c] = f2bf(f[c]);
        lo[c] = f2bf(f[c] - bf2f(hi[c]));
      }
      uint off = (uint)(r * 128 + sk * 2) ^ (uint)((r & 7) << 4);
      *(ushort4*)((char*)Ahi + off) = make_ushort4(hi[0], hi[1], hi[2], hi[3]);
      *(ushort4*)((char*)Alo + off) = make_ushort4(lo[0], lo[1], lo[2], lo[3]);
    }
#pragma unroll
    for (int p = 0; p < 8; ++p) {       // stage B (Wo rows -> bf16)
      int r = sr + 32 * p;
      float4 v = *(const float4*)(Wo + (size_t)(n0 + r) * HID + kt + sk);
      uint off = (uint)(r * 128 + sk * 2) ^ (uint)((r & 7) << 4);
      *(ushort4*)((char*)Bs + off) =
          make_ushort4(f2bf(v.x), f2bf(v.y), f2bf(v.z), f2bf(v.w));
    }
    __syncthreads();

    const int fr = lane & 15, kg = lane >> 4;
#pragma unroll
    for (int kk = 0; kk < 2; ++kk) {
      short8 bf[8], ah[4], al[4];
#pragma unroll
      for (int nf = 0; nf < 8; ++nf) {
        int row = wn * 128 + nf * 16 + fr;
        uint off = (uint)(row * 128 + kk * 64 + kg * 16) ^ (uint)((row & 7) << 4);
        bf[nf] = *(const short8*)((const char*)Bs + off);
      }
#pragma unroll
      for (int mf = 0; mf < 4; ++mf) {
        int row = wm * 64 + mf * 16 + fr;
        uint off = (uint)(row * 128 + kk * 64 + kg * 16) ^ (uint)((row & 7) << 4);
        ah[mf] = *(const short8*)((const char*)Ahi + off);
        al[mf] = *(const short8*)((const char*)Alo + off);
      }
#pragma unroll
      for (int mf = 0; mf < 4; ++mf)
#pragma unroll
        for (int nf = 0; nf < 8; ++nf) {
          acc[mf][nf] = __builtin_amdgcn_mfma_f32_16x16x32_bf16(
              ah[mf], bf[nf], acc[mf][nf], 0, 0, 0);
          acc[mf][nf] = __builtin_amdgcn_mfma_f32_16x16x32_bf16(
              al[mf], bf[nf], acc[mf][nf], 0, 0, 0);
        }
    }
  }

  const int fr = lane & 15, rg = lane >> 4;
#pragma unroll
  for (int mf = 0; mf < 4; ++mf)
#pragma unroll
    for (int nf = 0; nf < 8; ++nf) {
      int n = n0 + wn * 128 + nf * 16 + fr;
      float bb = bo[n];
#pragma unroll
      for (int j = 0; j < 4; ++j) {
        int m = m0 + wm * 64 + mf * 16 + rg * 4 + j;
        out[(size_t)m * VOCAB + n] = acc[mf][nf][j] + bb;
      }
    }
}

// hidden[0][b][n] = h0 step 255 (parity 1); hidden[1][b][n] = tops[255]
__global__ void copy_hidden(const float* __restrict__ h0g,
                            const float* __restrict__ tops,
                            float* __restrict__ outh)
{
  int i = blockIdx.x * 256 + threadIdx.x;   // 0..32767
  int l = i >> 14, rem = i & 16383;
  outh[i] = (l == 0) ? h0g[BATCH * HID + rem]
                     : tops[(size_t)(SEQ - 1) * (BATCH * HID) + rem];
}

extern "C" void kernel_launch(void* const* d_in, const int* in_sizes, int n_in,
                              void* d_out, int out_size, void* d_ws, size_t ws_size,
                              hipStream_t stream)
{
  const int*   x     = (const int*)d_in[0];
  const float* embed = (const float*)d_in[1];
  const float* Wi    = (const float*)d_in[2];
  const float* bi    = (const float*)d_in[3];
  const float* Wh    = (const float*)d_in[4];
  const float* bh    = (const float*)d_in[5];
  const float* Wo    = (const float*)d_in[6];
  const float* bo    = (const float*)d_in[7];
  float* out = (float*)d_out;

  char* ws = (char*)d_ws;
  float* pre0 = (float*)(ws);                          // 16 MiB [t][b][n]
  float* tops = (float*)(ws + (16u << 20));            // 16 MiB [t][b][n]
  float* h0g  = (float*)(ws + (32u << 20));            // 2 x 64 KiB
  float* h1g  = (float*)(ws + (32u << 20) + 131072);   // 2 x 64 KiB
  int*   bar  = (int*)  (ws + (32u << 20) + 262144);   // barrier counter

  // zero h parities + barrier counter (deterministic across replays)
  hipMemsetAsync(h0g, 0, 262144 + 4096, stream);

  pre0_gemm<<<dim3(8, 32), dim3(256), 0, stream>>>(x, embed, Wi, bi, bh, pre0);

  void* args[] = { (void*)&Wi, (void*)&Wh, (void*)&bi, (void*)&bh,
                   (void*)&pre0, (void*)&h0g, (void*)&h1g, (void*)&tops,
                   (void*)&bar };
  hipLaunchCooperativeKernel((void*)rnn_scan, dim3(NBLK), dim3(512), args, 0, stream);

  proj_mfma<<<dim3(16, 125), dim3(512), 0, stream>>>(tops, Wo, bo, out);

  copy_hidden<<<dim3(128), dim3(256), 0, stream>>>(
      h0g, tops, out + (size_t)BATCH * SEQ * VOCAB);
}